// Round 5
// baseline (106.743 us; speedup 1.0000x reference)
//
#include <hip/hip_runtime.h>
#include <math.h>

#define NB 8
#define KC 64
#define S1C 5
#define CC 128
#define PP 1936
#define MM 320             /* KC*S1C */
#define PT 64
#define NPT 31             /* ceil(1936/64) */
#define NTILE (NB * NPT)   /* 248 */
#define ALPHAF 1500.0f
#define EPSF 1e-12f

/* main-path ws (floats): part[248][64][128] ; ps[248][64] */
#define WS_PS   (NTILE * KC * CC)
#define WS_MAIN_FLOATS (WS_PS + NTILE * KC)    /* 8.19 MB */
#define WS_FB_ZERO_BYTES ((size_t)(NB * KC * CC + NB * KC) * 4)

typedef __attribute__((ext_vector_type(8))) short short8;
typedef __attribute__((ext_vector_type(4))) float f32x4;

/* pack fp32 -> (bf16_hi << 16) | bf16_lo  (hi = truncate, lo = residual) */
__device__ __forceinline__ unsigned pack_bf16s(float x) {
    unsigned u  = __float_as_uint(x);
    unsigned hi = u & 0xffff0000u;
    float lo    = x - __uint_as_float(hi);
    return hi | (__float_as_uint(lo) >> 16);
}

/* xp column mapping: element (p,c) lives at dword p*132 + 4*(((c>>2)+(p>>2))&31) + (c&3)
   -> logits b128 reads conflict-free, staging writes 2-way, B-frag b32 reads 2-way */
#define XPROW 132
__device__ __forceinline__ int xp_addr(int p, int c) {
    return p * XPROW + 4 * (((c >> 2) + (p >> 2)) & 31) + (c & 3);
}

// ---------------------------------------------------------------------------
// k1: per (n, p-tile of 64), 1024 threads = 16 waves, 3 barriers.
// Phases: stage(x->packed bf16 LDS, bias) | logits fp32-VALU (x=hi+lo) |
//         softmax (reg partials, all-thread finalize) + sa/wa/ps |
//         stage-C via bf16-split MFMA -> slab (mode0) or atomics (mode1)
// ---------------------------------------------------------------------------
__global__ __launch_bounds__(1024, 4) void k1_main(
    const float* __restrict__ x, const float* __restrict__ cen,
    float* __restrict__ sa_out, float* __restrict__ outC,
    float* __restrict__ outS, int mode)
{
    __shared__ unsigned xp[64 * XPROW];     // 33,792 B  packed x, [p][c-swizzled]
    __shared__ unsigned wap[KC * 68];       // 17,408 B  packed wa, [k][p] (+4 pad)
    __shared__ float    pmpe[16 * PT * 2];  //  8,192 B  per-wave alpha partials
    __shared__ float    bias[MM];           //  1,280 B

    const int tid  = threadIdx.x;
    const int lane = tid & 63;
    const int wid  = tid >> 6;      // 0..15
    const int bx   = blockIdx.x;
    const int n    = bx / NPT;
    const int pt   = bx - n * NPT;
    const int p0   = pt * PT;

    // ---- stage: x[n][c][p0..p0+63] -> packed bf16 hi|lo, transposed ----
    const float* xn = x + (size_t)n * CC * PP;
    for (int idx = tid; idx < CC * 16; idx += 1024) {
        const int c = idx >> 4;
        const int q = idx & 15;     // p-local = 4q+j
        const int p = p0 + q * 4;
        float4 v = make_float4(0.f, 0.f, 0.f, 0.f);
        if (p < PP) v = *(const float4*)(xn + (size_t)c * PP + p);  // PP%4==0
        xp[xp_addr(4 * q + 0, c)] = pack_bf16s(v.x);
        xp[xp_addr(4 * q + 1, c)] = pack_bf16s(v.y);
        xp[xp_addr(4 * q + 2, c)] = pack_bf16s(v.z);
        xp[xp_addr(4 * q + 3, c)] = pack_bf16s(v.w);
    }
    if (tid < MM) {   // bias[m] = -ALPHA*||cen_m||
        const float4* row = (const float4*)(cen + (size_t)tid * CC);
        float ss = 0.f;
#pragma unroll
        for (int c4 = 0; c4 < 32; ++c4) {
            const float4 v = row[c4];
            ss += v.x * v.x + v.y * v.y + v.z * v.z + v.w * v.w;
        }
        bias[tid] = -ALPHAF * sqrtf(ss);
    }
    __syncthreads();

    // ---- logits: 4 k per wave (wave-uniform), x reconstructed hi+lo ----
    const float4* w4[4];
#pragma unroll
    for (int i = 0; i < 4; ++i) {
        const int k = __builtin_amdgcn_readfirstlane(wid + 16 * i);
        w4[i] = (const float4*)(cen + (size_t)k * S1C * CC);
    }
    float acc[4][5];
#pragma unroll
    for (int i = 0; i < 4; ++i)
#pragma unroll
        for (int s = 0; s < 5; ++s) acc[i][s] = 0.f;

#pragma unroll 2
    for (int c4 = 0; c4 < 32; ++c4) {
        const int4 dw = *(const int4*)(&xp[lane * XPROW +
                                          4 * ((c4 + (lane >> 2)) & 31)]);
        const float x0 = __uint_as_float((unsigned)dw.x & 0xffff0000u) +
                         __uint_as_float((unsigned)dw.x << 16);
        const float x1 = __uint_as_float((unsigned)dw.y & 0xffff0000u) +
                         __uint_as_float((unsigned)dw.y << 16);
        const float x2 = __uint_as_float((unsigned)dw.z & 0xffff0000u) +
                         __uint_as_float((unsigned)dw.z << 16);
        const float x3 = __uint_as_float((unsigned)dw.w & 0xffff0000u) +
                         __uint_as_float((unsigned)dw.w << 16);
#pragma unroll
        for (int i = 0; i < 4; ++i) {
#pragma unroll
            for (int s = 0; s < 5; ++s) {
                const float4 w = w4[i][s * 32 + c4];
                acc[i][s] += w.x * x0 + w.y * x1 + w.z * x2 + w.w * x3;
            }
        }
    }

    float lg0_r[4], beta_r[4];
#pragma unroll
    for (int i = 0; i < 4; ++i) {
        const int k = wid + 16 * i;
        float lg[5];
#pragma unroll
        for (int s = 0; s < 5; ++s)
            lg[s] = 2.f * ALPHAF * acc[i][s] + bias[k * S1C + s];
        const float m5 = fmaxf(fmaxf(fmaxf(lg[0], lg[1]), fmaxf(lg[2], lg[3])), lg[4]);
        const float e0 = __expf(lg[0] - m5);
        const float den = e0 + __expf(lg[1] - m5) + __expf(lg[2] - m5) +
                          __expf(lg[3] - m5) + __expf(lg[4] - m5);
        beta_r[i] = e0 / den;
        lg0_r[i]  = lg[0];
    }
    // per-wave alpha partial (registers only)
    {
        float mx = fmaxf(fmaxf(lg0_r[0], lg0_r[1]), fmaxf(lg0_r[2], lg0_r[3]));
        float se = __expf(lg0_r[0] - mx) + __expf(lg0_r[1] - mx) +
                   __expf(lg0_r[2] - mx) + __expf(lg0_r[3] - mx);
        *(float2*)(&pmpe[(wid * PT + lane) * 2]) = make_float2(mx, se);
    }
    __syncthreads();

    // ---- alpha finalize (every thread, redundantly, for its own lane) ----
    float2 pv[16];
#pragma unroll
    for (int w = 0; w < 16; ++w)
        pv[w] = *(const float2*)(&pmpe[(w * PT + lane) * 2]);
    float gm = pv[0].x;
#pragma unroll
    for (int w = 1; w < 16; ++w) gm = fmaxf(gm, pv[w].x);
    float s = 0.f;
#pragma unroll
    for (int w = 0; w < 16; ++w) s += pv[w].y * __expf(pv[w].x - gm);
    const float arcs = 1.0f / s;

    // ---- sa out + packed wa into LDS + ps via shfl reduction ----
    const bool valid = (p0 + lane) < PP;
    float* san = sa_out + (size_t)n * KC * PP;
#pragma unroll
    for (int i = 0; i < 4; ++i) {
        const int k = wid + 16 * i;
        const float sa = __expf(lg0_r[i] - gm) * arcs * beta_r[i];
        if (valid) san[(size_t)k * PP + p0 + lane] = sa;
        const float wa = valid ? (1.0f + sa) : 0.0f;
        wap[k * 68 + lane] = pack_bf16s(wa);
        float ssum = wa;
#pragma unroll
        for (int off = 1; off < 64; off <<= 1) ssum += __shfl_xor(ssum, off);
        if (lane == 0) {
            if (mode == 0) outS[(size_t)bx * KC + k] = ssum;
            else           atomicAdd(&outS[n * KC + k], ssum);
        }
    }
    __syncthreads();

    // ---- stage-C: C[k][c] = sum_p wa*x via bf16-split MFMA ----
    // wave -> k-tile (wid&3), c-tiles 2*(wid>>2), 2*(wid>>2)+1
    const int kt  = wid & 3;
    const int ct0 = (wid >> 2) * 2;
    const int l15 = lane & 15;
    const int l4  = lane >> 4;
    f32x4 dacc[2];
    dacc[0] = (f32x4){0.f, 0.f, 0.f, 0.f};
    dacc[1] = (f32x4){0.f, 0.f, 0.f, 0.f};

#pragma unroll
    for (int ks = 0; ks < 64; ks += 32) {
        // A-frags (wa): rows 16*kt+l15, cols ks + l4*8 + 0..7
        const int abase = (16 * kt + l15) * 68 + ks + l4 * 8;
        const int4 qa0 = *(const int4*)(&wap[abase]);
        const int4 qa1 = *(const int4*)(&wap[abase + 4]);
        int adw[8] = {qa0.x, qa0.y, qa0.z, qa0.w, qa1.x, qa1.y, qa1.z, qa1.w};
        short8 ah, al;
#pragma unroll
        for (int j = 0; j < 8; ++j) {
            ah[j] = (short)((unsigned)adw[j] >> 16);
            al[j] = (short)((unsigned)adw[j] & 0xffffu);
        }
#pragma unroll
        for (int t = 0; t < 2; ++t) {
            const int c = 16 * (ct0 + t) + l15;
            int bdw[8];
#pragma unroll
            for (int j = 0; j < 8; ++j)
                bdw[j] = (int)xp[xp_addr(ks + l4 * 8 + j, c)];
            short8 bh, bl;
#pragma unroll
            for (int j = 0; j < 8; ++j) {
                bh[j] = (short)((unsigned)bdw[j] >> 16);
                bl[j] = (short)((unsigned)bdw[j] & 0xffffu);
            }
            dacc[t] = __builtin_amdgcn_mfma_f32_16x16x32_bf16(ah, bh, dacc[t], 0, 0, 0);
            dacc[t] = __builtin_amdgcn_mfma_f32_16x16x32_bf16(ah, bl, dacc[t], 0, 0, 0);
            dacc[t] = __builtin_amdgcn_mfma_f32_16x16x32_bf16(al, bh, dacc[t], 0, 0, 0);
        }
    }
    // D layout: col = lane&15, row = (lane>>4)*4 + reg
    if (mode == 0) {
        float* dst = outC + (size_t)bx * KC * CC;
#pragma unroll
        for (int t = 0; t < 2; ++t) {
            const int c = 16 * (ct0 + t) + l15;
#pragma unroll
            for (int r = 0; r < 4; ++r)
                dst[(16 * kt + 4 * l4 + r) * CC + c] = dacc[t][r];
        }
    } else {
        float* dst = outC + (size_t)n * KC * CC;
#pragma unroll
        for (int t = 0; t < 2; ++t) {
            const int c = 16 * (ct0 + t) + l15;
#pragma unroll
            for (int r = 0; r < 4; ++r)
                atomicAdd(&dst[(16 * kt + 4 * l4 + r) * CC + c], dacc[t][r]);
        }
    }
}

// ---------------------------------------------------------------------------
// k2 (slab mode): reduce 31 partial slabs, subtract rep*Swa, normalize, /8
// ---------------------------------------------------------------------------
__global__ __launch_bounds__(128) void k2_slab(
    const float* __restrict__ part, const float* __restrict__ ps,
    const float* __restrict__ cen, float* __restrict__ flat)
{
    __shared__ float w2[2];
    const int b = blockIdx.x;        // n*64 + k
    const int n = b >> 6;
    const int k = b & 63;
    const int c = threadIdx.x;       // 0..127
    const float* pb = part + ((size_t)n * NPT) * KC * CC + (size_t)k * CC + c;
    float v = 0.f;
#pragma unroll 8
    for (int pt = 0; pt < NPT; ++pt) v += pb[(size_t)pt * KC * CC];
    const float* psb = ps + (size_t)n * NPT * KC + k;
    float sw = 0.f;
#pragma unroll
    for (int pt = 0; pt < NPT; ++pt) sw += psb[(size_t)pt * KC];
    v -= cen[(size_t)k * S1C * CC + c] * sw;

    float ss = v * v;
#pragma unroll
    for (int off = 32; off > 0; off >>= 1) ss += __shfl_down(ss, off);
    if ((c & 63) == 0) w2[c >> 6] = ss;
    __syncthreads();
    const float norm = sqrtf(w2[0] + w2[1]);
    // flat-level norm is exactly sqrt(64)=8 (every row unit-norm, >> EPS)
    const float scale = 1.0f / (fmaxf(norm, EPSF) * 8.0f);
    flat[(size_t)b * CC + c] = v * scale;
}

// ---------------------------------------------------------------------------
// k2 (fallback/atomic mode)
// ---------------------------------------------------------------------------
__global__ __launch_bounds__(128) void k2_final(
    const float* __restrict__ accC, const float* __restrict__ accS,
    const float* __restrict__ cen, float* __restrict__ flat)
{
    __shared__ float w2[2];
    const int b = blockIdx.x;
    const int k = b & 63;
    const int c = threadIdx.x;
    const float v = accC[(size_t)b * CC + c] -
                    cen[(size_t)k * S1C * CC + c] * accS[b];
    float ss = v * v;
#pragma unroll
    for (int off = 32; off > 0; off >>= 1) ss += __shfl_down(ss, off);
    if ((c & 63) == 0) w2[c >> 6] = ss;
    __syncthreads();
    const float norm = sqrtf(w2[0] + w2[1]);
    const float scale = 1.0f / (fmaxf(norm, EPSF) * 8.0f);
    flat[(size_t)b * CC + c] = v * scale;
}

// ---------------------------------------------------------------------------
extern "C" void kernel_launch(void* const* d_in, const int* in_sizes, int n_in,
                              void* d_out, int out_size, void* d_ws, size_t ws_size,
                              hipStream_t stream) {
    const float* x   = (const float*)d_in[0];   // [8][128][44][44]
    const float* cen = (const float*)d_in[1];   // [64][5][128]
    float* out  = (float*)d_out;
    float* flat = out;                           // [8][8192]
    float* sa   = out + (size_t)NB * KC * CC;    // [8][64][1][1936]
    float* ws   = (float*)d_ws;

    if (ws_size >= (size_t)WS_MAIN_FLOATS * 4) {
        float* part = ws;
        float* ps   = ws + WS_PS;
        k1_main<<<NTILE, 1024, 0, stream>>>(x, cen, sa, part, ps, 0);
        k2_slab<<<NB * KC, 128, 0, stream>>>(part, ps, cen, flat);
    } else {
        float* accC = ws;
        float* accS = ws + NB * KC * CC;
        hipMemsetAsync(d_ws, 0, WS_FB_ZERO_BYTES, stream);
        k1_main<<<NTILE, 1024, 0, stream>>>(x, cen, sa, accC, accS, 1);
        k2_final<<<NB * KC, 128, 0, stream>>>(accC, accS, cen, flat);
    }
}